// Round 4
// baseline (84.853 us; speedup 1.0000x reference)
//
#include <hip/hip_runtime.h>

// B=32, G=512
// out layout: [rel_pos (B,G,G,3) | rel_ori (B,G,G,3,3)] flat f32
//
// Wave-local barrier-free pipeline: each wave owns a 12KB LDS slice and
// processes 256-j chunks (compute -> ds_write -> lgkmcnt(0) -> ds_read ->
// contiguous float4 stores). No __syncthreads anywhere, so global stores
// never drain at a barrier; wave-scope fences provide the intra-wave
// LDS ordering the compiler needs.

#define G_ 512
#define NB 32

__global__ __launch_bounds__(256) void relposori_kernel(
    const float* __restrict__ center,   // (B,G,6)
    const float* __restrict__ lrf,      // (B,G,3,3)
    float* __restrict__ out_pos,        // (B,G,G,3)
    float* __restrict__ out_ori)        // (B,G,G,3,3)
{
    __shared__ float s[4 * 3072];       // 48 KB: per wave 3072 floats
    int tid  = threadIdx.x;
    int lane = tid & 63;
    int w    = tid >> 6;
    float* sp = s + w * 3072;           // 768 floats: pos chunk (256 j * 3)
    float* so = sp + 768;               // 2304 floats: ori chunk (256 j * 9)

    const int nchunks = NB * G_ * 2;    // 32768 chunks of 256 j
    const int nwaves  = gridDim.x * 4;  // 2048 -> exactly 16 chunks/wave
    int cw = blockIdx.x * 4 + w;

    for (int c = cw; c < nchunks; c += nwaves) {
        int bi = c >> 1;                // b*512 + i (wave-uniform)
        int b  = bi >> 9;
        int j0 = (c & 1) << 8;

        const float* ci = center + (size_t)bi * 6;
        const float* li = lrf    + (size_t)bi * 9;
        float ci0 = ci[0], ci1 = ci[1], ci2 = ci[2];
        float li_[9];
#pragma unroll
        for (int t = 0; t < 9; ++t) li_[t] = li[t];

#pragma unroll
        for (int q = 0; q < 4; ++q) {
            int jl = (q << 6) + lane;   // 0..255 within chunk
            size_t bj = (size_t)b * G_ + (size_t)(j0 + jl);
            const float* cj = center + bj * 6;
            const float* lj = lrf    + bj * 9;
            float d0 = cj[0] - ci0, d1 = cj[1] - ci1, d2 = cj[2] - ci2;
            float lj_[9];
#pragma unroll
            for (int t = 0; t < 9; ++t) lj_[t] = lj[t];

            // rel_pos[k] = sum_c d[c] * lrf_i[c][k]
#pragma unroll
            for (int k = 0; k < 3; ++k)
                sp[jl * 3 + k] = d0 * li_[k] + d1 * li_[3 + k] + d2 * li_[6 + k];

            // rel_ori[m][n] = sum_k lrf_i[k][m] * lrf_j[k][n]
#pragma unroll
            for (int m = 0; m < 3; ++m)
#pragma unroll
                for (int n = 0; n < 3; ++n)
                    so[jl * 9 + m * 3 + n] = li_[m]     * lj_[n]
                                           + li_[3 + m] * lj_[3 + n]
                                           + li_[6 + m] * lj_[6 + n];
        }

        // Intra-wave RAW fence: LDS writes visible before cross-lane reads.
        // "memory" clobber orders the DS ops at compile time; lgkmcnt(0)
        // waits only for LDS (global stores in flight are NOT drained).
        asm volatile("s_waitcnt lgkmcnt(0)" ::: "memory");
        __builtin_amdgcn_sched_barrier(0);

        // Wave-local writeback: perfectly contiguous, 16B-aligned float4 runs.
        size_t row = (size_t)bi * G_ + (size_t)j0;
        const float4* sp4 = (const float4*)sp;
        float4* op4 = (float4*)(out_pos + row * 3);
#pragma unroll
        for (int t = 0; t < 3; ++t)             // 192 float4 / 64 lanes
            op4[(t << 6) + lane] = sp4[(t << 6) + lane];

        const float4* so4 = (const float4*)so;
        float4* oo4 = (float4*)(out_ori + row * 9);
#pragma unroll
        for (int t = 0; t < 9; ++t)             // 576 float4 / 64 lanes
            oo4[(t << 6) + lane] = so4[(t << 6) + lane];

        // WAR fence: next iteration's ds_writes must not be hoisted above
        // this iteration's ds_reads (same LDS slice).
        asm volatile("" ::: "memory");
        __builtin_amdgcn_wave_barrier();
    }
}

extern "C" void kernel_launch(void* const* d_in, const int* in_sizes, int n_in,
                              void* d_out, int out_size, void* d_ws, size_t ws_size,
                              hipStream_t stream) {
    const float* center = (const float*)d_in[0];
    const float* lrf    = (const float*)d_in[1];
    float* out = (float*)d_out;

    const int B = 32;
    const size_t n_pos = (size_t)B * G_ * G_ * 3;   // 25,165,824 floats
    float* out_pos = out;
    float* out_ori = out + n_pos;

    dim3 grid(512);     // 2048 waves -> 16 chunks each, perfectly balanced
    dim3 block(256);
    hipLaunchKernelGGL(relposori_kernel, grid, block, 0, stream,
                       center, lrf, out_pos, out_ori);
}

// Round 5
// 80.678 us; speedup vs baseline: 1.0518x; 1.0518x over previous
//
#include <hip/hip_runtime.h>

// B=32, G=512
// out layout: [rel_pos (B,G,G,3) | rel_ori (B,G,G,3,3)] flat f32
//
// Barrier-free wave-local pipeline at MAX occupancy:
//  - chunk = 64 j values; per-wave LDS slice = 64*12 floats = 3 KB
//  - block = 256 thr (4 waves) -> 12 KB LDS -> 8 blocks/CU = 32 waves/CU
//  - grid = 2048 blocks = exact resident capacity; 16 chunks/wave, no tail
//  - no __syncthreads (no vmcnt drain); wave-scope lgkmcnt fences only

#define G_ 512
#define NB 32

__global__ __launch_bounds__(256, 8) void relposori_kernel(
    const float* __restrict__ center,   // (B,G,6)
    const float* __restrict__ lrf,      // (B,G,3,3)
    float* __restrict__ out_pos,        // (B,G,G,3)
    float* __restrict__ out_ori)        // (B,G,G,3,3)
{
    __shared__ float s[4 * 768];        // 12 KB: 768 floats per wave
    int tid  = threadIdx.x;
    int lane = tid & 63;
    int w    = tid >> 6;
    float* sp = s + w * 768;            // 192 floats: pos (64 j * 3)
    float* so = sp + 192;               // 576 floats: ori (64 j * 9)

    const int nchunks = NB * G_ * 8;    // 131072 chunks of 64 j
    const int nwaves  = 2048 * 4;       // 8192 -> exactly 16 chunks/wave
    int wave_id = __builtin_amdgcn_readfirstlane(blockIdx.x * 4 + w);

    for (int c = wave_id; c < nchunks; c += nwaves) {
        int bi = c >> 3;                // b*512 + i  (scalar)
        int b  = bi >> 9;
        int q  = c & 7;
        int j0 = q << 6;

        // wave-uniform loads (scalar path): center_i, lrf_i
        const float* ci = center + (size_t)bi * 6;
        const float* li = lrf    + (size_t)bi * 9;
        float ci0 = ci[0], ci1 = ci[1], ci2 = ci[2];
        float li_[9];
#pragma unroll
        for (int t = 0; t < 9; ++t) li_[t] = li[t];

        // per-lane j
        int j = j0 + lane;
        size_t bj = (size_t)b * G_ + (size_t)j;
        const float* cj = center + bj * 6;
        const float* lj = lrf    + bj * 9;
        float d0 = cj[0] - ci0, d1 = cj[1] - ci1, d2 = cj[2] - ci2;
        float lj_[9];
#pragma unroll
        for (int t = 0; t < 9; ++t) lj_[t] = lj[t];

        // rel_pos[k] = sum_c d[c] * lrf_i[c][k]
#pragma unroll
        for (int k = 0; k < 3; ++k)
            sp[lane * 3 + k] = d0 * li_[k] + d1 * li_[3 + k] + d2 * li_[6 + k];

        // rel_ori[m][n] = sum_k lrf_i[k][m] * lrf_j[k][n]
#pragma unroll
        for (int m = 0; m < 3; ++m)
#pragma unroll
            for (int n = 0; n < 3; ++n)
                so[lane * 9 + m * 3 + n] = li_[m]     * lj_[n]
                                         + li_[3 + m] * lj_[3 + n]
                                         + li_[6 + m] * lj_[6 + n];

        // Intra-wave RAW fence: LDS writes visible before cross-lane reads.
        // Waits only lgkmcnt -- in-flight global stores are NOT drained.
        asm volatile("s_waitcnt lgkmcnt(0)" ::: "memory");
        __builtin_amdgcn_sched_barrier(0);

        // Coalesced 16B-aligned float4 writeback of this 64-j span.
        const float4* sp4 = (const float4*)sp;
        const float4* so4 = (const float4*)so;
        float4* op4 = (float4*)out_pos + ((size_t)bi * 384 + 48 * q);   // 48 f4
        float4* oo4 = (float4*)out_ori + ((size_t)bi * 1152 + 144 * q); // 144 f4

        if (lane < 48) op4[lane] = sp4[lane];
        oo4[lane]      = so4[lane];
        oo4[64 + lane] = so4[64 + lane];
        if (lane < 16) oo4[128 + lane] = so4[128 + lane];

        // WAR fence: next iteration's ds_writes must not hoist above reads.
        asm volatile("" ::: "memory");
        __builtin_amdgcn_wave_barrier();
    }
}

extern "C" void kernel_launch(void* const* d_in, const int* in_sizes, int n_in,
                              void* d_out, int out_size, void* d_ws, size_t ws_size,
                              hipStream_t stream) {
    const float* center = (const float*)d_in[0];
    const float* lrf    = (const float*)d_in[1];
    float* out = (float*)d_out;

    const int B = 32;
    const size_t n_pos = (size_t)B * G_ * G_ * 3;   // 25,165,824 floats
    float* out_pos = out;
    float* out_ori = out + n_pos;

    dim3 grid(2048);    // = 8 blocks/CU * 256 CU, all resident, 16 chunks/wave
    dim3 block(256);
    hipLaunchKernelGGL(relposori_kernel, grid, block, 0, stream,
                       center, lrf, out_pos, out_ori);
}